// Round 17
// baseline (79.524 us; speedup 1.0000x reference)
//
#include <hip/hip_runtime.h>
#include <stdint.h>

#define T_LEN 512
#define I_LEN 5
#define CHUNK 8                    // timesteps per staged chunk
#define NCHUNK 64                  // T_LEN / CHUNK

// __fp16 matches __builtin_amdgcn_cvt_pkrtz's return element type
typedef __fp16 h2_t __attribute__((ext_vector_type(2)));
typedef __fp16 h4_t __attribute__((ext_vector_type(4)));
typedef float  f4v  __attribute__((ext_vector_type(4)));

// global -> LDS direct DMA, 16B/lane, LDS dst = wave-uniform base + lane*16
__device__ __forceinline__ void gload_lds16(const float* g, float* l) {
    auto gp = reinterpret_cast<const __attribute__((address_space(1))) float*>(
        reinterpret_cast<uintptr_t>(g));
    auto lp = reinterpret_cast<__attribute__((address_space(3))) float*>(
        reinterpret_cast<uintptr_t>(l));
    __builtin_amdgcn_global_load_lds(gp, lp, 16, 0, 0);
}

// Volatile asm ds_read_b128: cannot be sunk or split (r11 lesson).
#define DSR(dst, addr, OFFSTR)                                              \
    asm volatile("ds_read_b128 %0, %1 offset:" OFFSTR                       \
                 : "=v"(dst) : "v"(addr))

#define DSR10(q, addr)                                                      \
    do {                                                                    \
        DSR((q)[0], (addr), "0");   DSR((q)[1], (addr), "16");              \
        DSR((q)[2], (addr), "32");  DSR((q)[3], (addr), "48");              \
        DSR((q)[4], (addr), "64");  DSR((q)[5], (addr), "80");              \
        DSR((q)[6], (addr), "96");  DSR((q)[7], (addr), "112");             \
        DSR((q)[8], (addr), "128"); DSR((q)[9], (addr), "144");             \
    } while (0)

#define WAIT_LGKM0()                                                        \
    do {                                                                    \
        asm volatile("s_waitcnt lgkmcnt(0)" ::: "memory");                  \
        __builtin_amdgcn_sched_barrier(0);                                  \
    } while (0)

#define WAIT_VM(N)                                                          \
    asm volatile("s_waitcnt vmcnt(" #N ")" ::: "memory")

// Component extract with compile-time-constant idx (free after unroll).
__device__ __forceinline__ float f4_at(const float4* b, int idx) {
    const float4 v = b[idx >> 2];
    switch (idx & 3) {
        case 0: return v.x;
        case 1: return v.y;
        case 2: return v.z;
        default: return v.w;
    }
}

// Padé tanh (verified r16): one transcendental, err <= 7.5e-3 on |z|<=5.
__device__ __forceinline__ float tanh_pade(float zin) {
    const float z = fminf(fmaxf(zin, -5.0f), 5.0f);
    const float t = z * z;
    const float np = __builtin_fmaf(t, t + 105.0f, 945.0f);
    const float dp = __builtin_fmaf(t, __builtin_fmaf(t, 15.0f, 420.0f),
                                    945.0f);
    return (z * np) * __builtin_amdgcn_rcpf(dp);
}

// r17: VALU x-projection (replaces the prep MFMA -> 1 MFMA/step total).
// Lane (g,bcol) computes xw[i] = cbias[i] + sum_k W_ih[4g+i][k]*x_t[k] for
// its 4 D-rows directly in f32 (more precise than the f16 MFMA it replaces).
__device__ __forceinline__ void prep_step_valu(const float4* __restrict__ q,
                                               int s,
                                               const float wih5[4][5],
                                               f4v cbias,
                                               f4v* __restrict__ xw) {
    const float e0 = f4_at(q, 5 * s + 0);
    const float e1 = f4_at(q, 5 * s + 1);
    const float e2 = f4_at(q, 5 * s + 2);
    const float e3 = f4_at(q, 5 * s + 3);
    const float e4 = f4_at(q, 5 * s + 4);
    f4v r;
#pragma unroll
    for (int i = 0; i < 4; ++i) {
        float a = __builtin_fmaf(e0, wih5[i][0], cbias[i]);
        float b = e1 * wih5[i][1];
        a = __builtin_fmaf(e2, wih5[i][2], a);
        b = __builtin_fmaf(e3, wih5[i][3], b);
        a = __builtin_fmaf(e4, wih5[i][4], a);
        r[i] = a + b;
    }
    xw[s] = r;
}

// Serial chain step (verified r16): acc = W_hh*h + xw; h' = tanh_pade(acc).
// D-grouping == B-grouping (verified r9): tanh(D) is directly next B frag.
__device__ __forceinline__ void chain_step(h4_t& bh, h4_t ahh, f4v xws) {
    f4v acc = __builtin_amdgcn_mfma_f32_16x16x16f16(ahh, bh, xws, 0, 0, 0);
    const float h0 = tanh_pade(acc[0]);
    const float h1 = tanh_pade(acc[1]);
    const float h2 = tanh_pade(acc[2]);
    const float h3 = tanh_pade(acc[3]);
    h2_t blo = __builtin_amdgcn_cvt_pkrtz(h0, h1);
    h2_t bhi = __builtin_amdgcn_cvt_pkrtz(h2, h3);
    bh = __builtin_shufflevector(blo, bhi, 0, 1, 2, 3);
}

__global__ __launch_bounds__(64) void rnn_m2o_kernel(
    const float* __restrict__ x, const float* __restrict__ W_ih,
    const float* __restrict__ W_hh, const float* __restrict__ b_ih,
    const float* __restrict__ b_hh, const float* __restrict__ W_fc,
    const float* __restrict__ b_fc, float* __restrict__ out)
{
    const int lane = threadIdx.x;      // one wave per block
    const int g    = lane >> 4;        // lane-group 0..3
    const int bcol = lane & 15;        // batch column (n of B/D), A row (m)
    const int bb   = blockIdx.x * 16;  // first batch of this wave

    __shared__ float lds[4 * 768];     // 4 slots x 3072 B (r12-verified)

    // Fragments (r9-verified mapping). A: m=lane&15, k=4g+i; C/D row=4g+i.
    h4_t ahh;
    f4v  cbias, wfc4;
    float wih5[4][5];
#pragma unroll
    for (int i = 0; i < 4; ++i) {
        const int k = 4 * g + i;
        ahh[i]   = (__fp16)W_hh[bcol * 16 + k];
        cbias[i] = b_ih[k] + b_hh[k];
        wfc4[i]  = W_fc[k];
#pragma unroll
        for (int kk = 0; kk < 5; ++kk)
            wih5[i][kk] = W_ih[k * I_LEN + kk];
    }
    const float bfc = b_fc[0];

    // Staging map (r9-verified): s = 64L + lane = 11*b + i; batch b at dword
    // 44b within the slot.
    const float* gsrc[3];
#pragma unroll
    for (int L = 0; L < 3; ++L) {
        const int s = 64 * L + lane;
        const int sb = s / 11, si = s % 11;
        const bool real = (s < 176) && (si < 10);
        gsrc[L] = x + (size_t)(bb + (real ? sb : 0)) * (T_LEN * I_LEN)
                    + (real ? si * 4 : 0);
    }

#define STAGE(n_)                                                           \
    do {                                                                    \
        const int off_ = ((n_) & (NCHUNK - 1)) * (CHUNK * I_LEN);           \
        float* dst_ = &lds[((n_) & 3) * 768];                               \
        gload_lds16(gsrc[0] + off_, dst_);                                  \
        gload_lds16(gsrc[1] + off_, dst_ + 256);                            \
        gload_lds16(gsrc[2] + off_, dst_ + 512);                            \
    } while (0)

    // Read base: my batch row (176B stride). No +16B group shift (that was
    // only for MFMA B-fragment slots); all 4 groups broadcast the same row.
    const uint32_t rbase = (uint32_t)(uintptr_t)&lds[0]
                         + (uint32_t)(bcol * 176);

    h4_t bh = (h4_t)0;                 // h_0 = 0

    f4v  xwA[8], xwB[8];
    float4 qU[10], qV[10];

    // Prologue (r12-verified): chains n | preps n+1 (qU) | DSRs n+2 (qV).
    STAGE(0); STAGE(1); STAGE(2);      // 9 DMAs in flight
    WAIT_VM(6);                        // chunk 0 landed
    DSR10(qV, rbase);                  // q_0 (temp in qV)
    WAIT_LGKM0();
#pragma unroll
    for (int s = 0; s < 8; ++s) prep_step_valu(qV, s, wih5, cbias, xwA);
    STAGE(3);
    WAIT_VM(6);                        // chunk 1 landed
    DSR10(qU, rbase + 1 * 3072);       // q_1
    WAIT_LGKM0();

    for (int n = 0; n < NCHUNK; n += 2) {
        {   // even region: chain n (xwA) ∥ prep n+1 (qU -> xwB); DSR n+2->qV
            STAGE(n + 4);
            WAIT_VM(6);                // chunk n+2 landed
            DSR10(qV, rbase + (uint32_t)(((n + 2) & 3) * 3072));
#pragma unroll
            for (int s = 0; s < 8; ++s) {
                chain_step(bh, ahh, xwA[s]);
                prep_step_valu(qU, s, wih5, cbias, xwB);
            }
            WAIT_LGKM0();
        }
        {   // odd region: chain n+1 (xwB) ∥ prep n+2 (qV -> xwA); DSR n+3->qU
            STAGE(n + 5);
            WAIT_VM(6);                // chunk n+3 landed
            DSR10(qU, rbase + (uint32_t)(((n + 3) & 3) * 3072));
#pragma unroll
            for (int s = 0; s < 8; ++s) {
                chain_step(bh, ahh, xwB[s]);
                prep_step_valu(qV, s, wih5, cbias, xwA);
            }
            WAIT_LGKM0();
        }
    }
    WAIT_VM(0);                        // drain tail DMAs

    // fc + sigmoid: unpack final h (f16, same values the recurrence used).
    float p = (float)bh[0] * wfc4[0] + (float)bh[1] * wfc4[1]
            + (float)bh[2] * wfc4[2] + (float)bh[3] * wfc4[3];
    p += __shfl_xor(p, 16);
    p += __shfl_xor(p, 32);
    if (lane < 16) {
        const float z = p + bfc;
        out[bb + lane] = __builtin_amdgcn_rcpf(
            1.0f + __builtin_exp2f(z * -1.4426950408889634f));
    }
#undef STAGE
}

extern "C" void kernel_launch(void* const* d_in, const int* in_sizes, int n_in,
                              void* d_out, int out_size, void* d_ws, size_t ws_size,
                              hipStream_t stream) {
    const float* x    = (const float*)d_in[0];
    const float* W_ih = (const float*)d_in[1];
    const float* W_hh = (const float*)d_in[2];
    const float* b_ih = (const float*)d_in[3];
    const float* b_hh = (const float*)d_in[4];
    const float* W_fc = (const float*)d_in[5];
    const float* b_fc = (const float*)d_in[6];
    float* out = (float*)d_out;

    const int B = in_sizes[0] / (T_LEN * I_LEN);   // 8192
    const int blocks = B / 16;                     // 16 batches per wave
    rnn_m2o_kernel<<<blocks, 64, 0, stream>>>(x, W_ih, W_hh, b_ih, b_hh,
                                              W_fc, b_fc, out);
}